// Round 5
// baseline (2416.615 us; speedup 1.0000x reference)
//
#include <hip/hip_runtime.h>
#include <hip/hip_bf16.h>

#define D 64
#define RSHIFT 9             // 512 nodes per dst-bucket
#define BNODES 512
#define MAXB 256             // >= nb = ceil(100000/512) = 196
#define BCAP 10240           // per-bucket edge capacity (mean 8192, sigma ~90)
#define SCAP 14336           // per-bucket PADDED ssrc capacity (edges + self + pad)
#define FH 72                // LDS row stride (bf16) for wt
#define HS 68                // LDS row stride (f32) for hacc: 16B-aligned, 4-bank skew

typedef unsigned short ushort_t;
typedef unsigned int uint_t;
typedef short short8 __attribute__((ext_vector_type(8)));   // 8 bf16 MFMA frag
typedef float floatx4 __attribute__((ext_vector_type(4)));  // MFMA C/D frag

__device__ inline uint_t pk_bf16(float x, float y) {
    uint_t ux = __float_as_uint(x); ux = ux + 0x7fffu + ((ux >> 16) & 1u);
    uint_t uy = __float_as_uint(y); uy = uy + 0x7fffu + ((uy >> 16) & 1u);
    return (ux >> 16) | (uy & 0xffff0000u);
}
__device__ inline ushort_t rnd_bf16(float x) {
    uint_t u = __float_as_uint(x); u = u + 0x7fffu + ((u >> 16) & 1u);
    return (ushort_t)(u >> 16);
}

// ---------------- stage 1: bucket edges by dst range ----------------
// Packed entry: (src << 9) | (dst & 511). NO per-edge global atomics.
__global__ __launch_bounds__(256) void k_bucket(const int* __restrict__ src,
                                                const int* __restrict__ dst,
                                                int* __restrict__ bcur,
                                                int* __restrict__ ebuf,
                                                int E, int nb) {
    __shared__ int lcnt[MAXB];
    __shared__ int lbase[MAXB];
    int t = threadIdx.x;
    lcnt[t] = 0;
    __syncthreads();
    int base = blockIdx.x * 2048 + t * 8;
    int sv[8], dv[8], sl[8];
    if (base + 7 < E) {
        int4 a0 = *(const int4*)(src + base);
        int4 a1 = *(const int4*)(src + base + 4);
        int4 b0 = *(const int4*)(dst + base);
        int4 b1 = *(const int4*)(dst + base + 4);
        sv[0]=a0.x; sv[1]=a0.y; sv[2]=a0.z; sv[3]=a0.w;
        sv[4]=a1.x; sv[5]=a1.y; sv[6]=a1.z; sv[7]=a1.w;
        dv[0]=b0.x; dv[1]=b0.y; dv[2]=b0.z; dv[3]=b0.w;
        dv[4]=b1.x; dv[5]=b1.y; dv[6]=b1.z; dv[7]=b1.w;
    } else {
        #pragma unroll
        for (int j = 0; j < 8; ++j) {
            dv[j] = (base + j < E) ? dst[base + j] : -1;
            sv[j] = (base + j < E) ? src[base + j] : 0;
        }
    }
    #pragma unroll
    for (int j = 0; j < 8; ++j) {
        if (dv[j] >= 0) {
            int b = dv[j] >> RSHIFT;
            sl[j] = atomicAdd(&lcnt[b], 1);   // LDS atomic only
        }
    }
    __syncthreads();
    if (t < nb) { int c = lcnt[t]; if (c) lbase[t] = atomicAdd(&bcur[t], c); }
    __syncthreads();
    #pragma unroll
    for (int j = 0; j < 8; ++j) {
        if (dv[j] >= 0) {
            int b = dv[j] >> RSHIFT;
            int slot = lbase[b] + sl[j];
            if (slot < BCAP)
                ebuf[(size_t)b * BCAP + slot] = (sv[j] << RSHIFT) | (dv[j] & (BNODES - 1));
        }
    }
}

// ---------------- stage 2: per-bucket CSR build, all atomics in LDS -------
// Emits packed edge words (src << 6) | dstLocal6 so the aggregation can be
// EDGE-CENTRIC (R4 post-mortem: pull-gather = per-node dependent chains,
// latency-bound at <25% on every pipe; per-thread state can't fix it
// without crossing the 64-VGPR occupancy cliff). Also appends an explicit
// self-edge per node and pads each segment to x8 with (N<<6) words that
// resolve to the zero row.
__global__ __launch_bounds__(256) void k_csr(const int* __restrict__ ebuf,
                                             const int* __restrict__ bcur,
                                             int2* __restrict__ rowse,
                                             int* __restrict__ ssrc,
                                             float* __restrict__ dis,
                                             int N, int nb) {
    __shared__ int sseg[BCAP];        // 40 KB edge stage
    __shared__ int lcnt[BNODES];
    __shared__ int lcur[BNODES];
    __shared__ int sums[256];
    int b = blockIdx.x;
    int t = threadIdx.x;
    int n = bcur[b];
    if (n > BCAP) n = BCAP;
    int node0 = b << RSHIFT;
    #pragma unroll
    for (int i = t; i < BNODES; i += 256) lcnt[i] = 0;
    __syncthreads();
    const int* seg = ebuf + (size_t)b * BCAP;
    // count + stage edges into LDS
    for (int i = t * 4; i < n; i += 1024) {
        if (i + 3 < n) {
            int4 e = *(const int4*)(seg + i);
            *(int4*)(sseg + i) = e;
            atomicAdd(&lcnt[e.x & (BNODES - 1)], 1);
            atomicAdd(&lcnt[e.y & (BNODES - 1)], 1);
            atomicAdd(&lcnt[e.z & (BNODES - 1)], 1);
            atomicAdd(&lcnt[e.w & (BNODES - 1)], 1);
        } else {
            for (int j = 0; j < 4 && i + j < n; ++j) {
                int e = seg[i + j];
                sseg[i + j] = e;
                atomicAdd(&lcnt[e & (BNODES - 1)], 1);
            }
        }
    }
    __syncthreads();
    int idx = t * 2;
    int v0 = lcnt[idx], v1 = lcnt[idx + 1];
    int p0 = (v0 + 8) & ~7;           // padded length incl. self-edge
    int p1 = (v1 + 8) & ~7;
    int s = p0 + p1;
    sums[t] = s;
    __syncthreads();
    for (int off = 1; off < 256; off <<= 1) {
        int x = (t >= off) ? sums[t - off] : 0;
        __syncthreads();
        sums[t] += x;
        __syncthreads();
    }
    int run = sums[t] - s;
    int beg0 = b * SCAP + run;
    int beg1 = beg0 + p0;
    lcur[idx] = beg0;
    lcur[idx + 1] = beg1;
    int node = node0 + idx;
    if (node < N) {
        rowse[node] = make_int2(beg0, beg0 + p0);
        dis[node] = rsqrtf((float)(v0 + 1));
        ssrc[beg0 + v0] = (node << 6) | (idx & 63);          // self-edge
        for (int k = v0 + 1; k < p0; ++k) ssrc[beg0 + k] = (N << 6);
    }
    if (node + 1 < N) {
        rowse[node + 1] = make_int2(beg1, beg1 + p1);
        dis[node + 1] = rsqrtf((float)(v1 + 1));
        ssrc[beg1 + v1] = ((node + 1) << 6) | ((idx + 1) & 63);
        for (int k = v1 + 1; k < p1; ++k) ssrc[beg1 + k] = (N << 6);
    }
    __syncthreads();
    // single scatter pass from LDS stage: packed (src<<6)|dstLocal6
    for (int i = t * 4; i < n; i += 1024) {
        if (i + 3 < n) {
            int4 e = *(const int4*)(sseg + i);
            int q0 = atomicAdd(&lcur[e.x & (BNODES - 1)], 1);
            ssrc[q0] = ((e.x >> RSHIFT) << 6) | (e.x & 63);
            int q1 = atomicAdd(&lcur[e.y & (BNODES - 1)], 1);
            ssrc[q1] = ((e.y >> RSHIFT) << 6) | (e.y & 63);
            int q2 = atomicAdd(&lcur[e.z & (BNODES - 1)], 1);
            ssrc[q2] = ((e.z >> RSHIFT) << 6) | (e.z & 63);
            int q3 = atomicAdd(&lcur[e.w & (BNODES - 1)], 1);
            ssrc[q3] = ((e.w >> RSHIFT) << 6) | (e.w & 63);
        } else {
            for (int j = 0; j < 4 && i + j < n; ++j) {
                int e = sseg[i + j];
                int q = atomicAdd(&lcur[e & (BNODES - 1)], 1);
                ssrc[q] = ((e >> RSHIFT) << 6) | (e & 63);
            }
        }
    }
}

// stage W^T as bf16 into LDS: wt[n][k] = bf16(W[k][n]) (validated R10)
__device__ __forceinline__ void stage_wt(const float* __restrict__ W,
                                         ushort_t* __restrict__ wt, int t) {
    const float4* W4 = (const float4*)W;
    for (int i = t; i < 1024; i += 256) {
        float4 w4 = W4[i];
        int k = i >> 4, n0 = (i & 15) * 4;
        wt[(n0 + 0) * FH + k] = rnd_bf16(w4.x);
        wt[(n0 + 1) * FH + k] = rnd_bf16(w4.y);
        wt[(n0 + 2) * FH + k] = rnd_bf16(w4.z);
        wt[(n0 + 3) * FH + k] = rnd_bf16(w4.w);
    }
}

// ---------------- layer-0 GEMM via MFMA: G = bf16((x@W)*dis) -------------
__global__ __launch_bounds__(256) void k_gemm0(const float* __restrict__ x,
                                               const float* __restrict__ W,
                                               const float* __restrict__ dis,
                                               ushort_t* __restrict__ G, int N) {
    __shared__ ushort_t wt[64 * FH];
    int t = threadIdx.x;
    stage_wt(W, wt, t);
    __syncthreads();
    int wv = t >> 6, lane = t & 63;
    int m = lane & 15, quad = lane >> 4;
    int row = blockIdx.x * 64 + wv * 16 + m;
    long rowc = (row < N) ? row : (N - 1);
    float4 f0 = *(const float4*)(x + rowc * D + quad * 8);
    float4 f1 = *(const float4*)(x + rowc * D + quad * 8 + 4);
    float4 f2 = *(const float4*)(x + rowc * D + 32 + quad * 8);
    float4 f3 = *(const float4*)(x + rowc * D + 32 + quad * 8 + 4);
    union { short8 s; uint_t u[4]; } a0, a1;
    a0.u[0] = pk_bf16(f0.x, f0.y); a0.u[1] = pk_bf16(f0.z, f0.w);
    a0.u[2] = pk_bf16(f1.x, f1.y); a0.u[3] = pk_bf16(f1.z, f1.w);
    a1.u[0] = pk_bf16(f2.x, f2.y); a1.u[1] = pk_bf16(f2.z, f2.w);
    a1.u[2] = pk_bf16(f3.x, f3.y); a1.u[3] = pk_bf16(f3.z, f3.w);
    floatx4 acc[4];
    #pragma unroll
    for (int j = 0; j < 4; ++j) {
        short8 b0 = *(short8*)&wt[(j * 16 + m) * FH + quad * 8];
        short8 b1 = *(short8*)&wt[(j * 16 + m) * FH + 32 + quad * 8];
        floatx4 z = {0.f, 0.f, 0.f, 0.f};
        acc[j] = __builtin_amdgcn_mfma_f32_16x16x32_bf16(a0.s, b0, z, 0, 0, 0);
        acc[j] = __builtin_amdgcn_mfma_f32_16x16x32_bf16(a1.s, b1, acc[j], 0, 0, 0);
    }
    int rbase = blockIdx.x * 64 + wv * 16 + quad * 4;
    #pragma unroll
    for (int r = 0; r < 4; ++r) {
        int rr = rbase + r;
        if (rr < N) {
            float sc = dis[rr];
            #pragma unroll
            for (int j = 0; j < 4; ++j)
                G[(size_t)rr * D + j * 16 + m] = rnd_bf16(acc[j][r] * sc);
        }
    }
}

// ---- edge-centric accumulation into LDS f32 tile ------------------------
// Each 8-lane group streams INDEPENDENT edges (word -> row -> 8 ds_add_f32):
// no per-node dependent chains. Unroll-4 + next-batch word prefetch keeps
// 4 row-loads in flight per lane. Pad/tail words = (N<<6): zero row, dl 0.
#define ROW(i) (*(const uint4*)(G + (size_t)(i) * D + c8))
#define ACCAT(d, u)                                                       \
    {                                                                     \
        float* hp = hacc + (d) * HS + c8;                                 \
        atomicAdd(hp + 0, __uint_as_float(u.x << 16));                    \
        atomicAdd(hp + 1, __uint_as_float(u.x & 0xffff0000u));            \
        atomicAdd(hp + 2, __uint_as_float(u.y << 16));                    \
        atomicAdd(hp + 3, __uint_as_float(u.y & 0xffff0000u));            \
        atomicAdd(hp + 4, __uint_as_float(u.z << 16));                    \
        atomicAdd(hp + 5, __uint_as_float(u.z & 0xffff0000u));            \
        atomicAdd(hp + 6, __uint_as_float(u.w << 16));                    \
        atomicAdd(hp + 7, __uint_as_float(u.w & 0xffff0000u));            \
    }

__device__ __forceinline__ void edge_accum(const ushort_t* __restrict__ G,
                                           const int* __restrict__ ssrc,
                                           float* hacc, int rs, int re,
                                           int gid, int c8, int NV) {
    int e0 = rs + gid * 4;
    int w0 = NV, w1 = NV, w2 = NV, w3 = NV;
    if (e0     < re) w0 = ssrc[e0];
    if (e0 + 1 < re) w1 = ssrc[e0 + 1];
    if (e0 + 2 < re) w2 = ssrc[e0 + 2];
    if (e0 + 3 < re) w3 = ssrc[e0 + 3];
    for (int e = e0; e < re; e += 128) {
        uint4 u0 = ROW(w0 >> 6), u1 = ROW(w1 >> 6);
        uint4 u2 = ROW(w2 >> 6), u3 = ROW(w3 >> 6);
        int d0 = w0 & 63, d1 = w1 & 63, d2 = w2 & 63, d3 = w3 & 63;
        int en = e + 128;
        w0 = NV; w1 = NV; w2 = NV; w3 = NV;
        if (en     < re) w0 = ssrc[en];
        if (en + 1 < re) w1 = ssrc[en + 1];
        if (en + 2 < re) w2 = ssrc[en + 2];
        if (en + 3 < re) w3 = ssrc[en + 3];
        ACCAT(d0, u0); ACCAT(d1, u1); ACCAT(d2, u2); ACCAT(d3, u3);
    }
}

// ---------------- fused agg + next-layer MFMA gemm -----------------------
// Phase 1: 32 groups stream the block's contiguous edge range into hacc.
// Phase 2: build A-frags directly from hacc (x di + bias), MFMA with wt.
__global__ __launch_bounds__(256) void k_fagg(const ushort_t* __restrict__ G,
                                              const float* __restrict__ dis,
                                              const int2* __restrict__ rowse,
                                              const int* __restrict__ ssrc,
                                              const float* __restrict__ bias,
                                              const float* __restrict__ W,
                                              ushort_t* __restrict__ Gout,
                                              int N) {
    __shared__ float hacc[64 * HS];       // 17.4 KB f32 accumulator tile
    __shared__ ushort_t wt[64 * FH];      // 9 KB W^T
    int t = threadIdx.x;
    stage_wt(W, wt, t);
    for (int i = t; i < 64 * HS; i += 256) hacc[i] = 0.f;
    int wv = t >> 6, lane = t & 63;
    int g = lane >> 3;
    int gid = wv * 8 + g;
    int c8 = (lane & 7) * 8;
    int gbase = blockIdx.x * 64;
    int last = gbase + 63; if (last > N - 1) last = N - 1;
    int rs = rowse[gbase].x;
    int re = rowse[last].y;
    int NV = N << 6;
    __syncthreads();
    edge_accum(G, ssrc, hacc, rs, re, gid, c8, NV);
    __syncthreads();
    // phase 2: A-frags from hacc (val = h*di + bias), MFMA (layout R10)
    int m = lane & 15, quad = lane >> 4;
    int r = wv * 16 + m;
    int row = gbase + r;
    float di = (row < N) ? dis[row] : 0.f;
    const float* hp = hacc + r * HS;
    float4 h0 = *(const float4*)(hp + quad * 8);
    float4 h1 = *(const float4*)(hp + quad * 8 + 4);
    float4 h2 = *(const float4*)(hp + 32 + quad * 8);
    float4 h3 = *(const float4*)(hp + 32 + quad * 8 + 4);
    float4 ba0 = *(const float4*)(bias + quad * 8);
    float4 ba1 = *(const float4*)(bias + quad * 8 + 4);
    float4 bb0 = *(const float4*)(bias + 32 + quad * 8);
    float4 bb1 = *(const float4*)(bias + 32 + quad * 8 + 4);
    union { short8 s; uint_t u[4]; } a0, a1;
    a0.u[0] = pk_bf16(h0.x * di + ba0.x, h0.y * di + ba0.y);
    a0.u[1] = pk_bf16(h0.z * di + ba0.z, h0.w * di + ba0.w);
    a0.u[2] = pk_bf16(h1.x * di + ba1.x, h1.y * di + ba1.y);
    a0.u[3] = pk_bf16(h1.z * di + ba1.z, h1.w * di + ba1.w);
    a1.u[0] = pk_bf16(h2.x * di + bb0.x, h2.y * di + bb0.y);
    a1.u[1] = pk_bf16(h2.z * di + bb0.z, h2.w * di + bb0.w);
    a1.u[2] = pk_bf16(h3.x * di + bb1.x, h3.y * di + bb1.y);
    a1.u[3] = pk_bf16(h3.z * di + bb1.z, h3.w * di + bb1.w);
    floatx4 acc[4];
    #pragma unroll
    for (int j = 0; j < 4; ++j) {
        short8 b0 = *(short8*)&wt[(j * 16 + m) * FH + quad * 8];
        short8 b1 = *(short8*)&wt[(j * 16 + m) * FH + 32 + quad * 8];
        floatx4 z = {0.f, 0.f, 0.f, 0.f};
        acc[j] = __builtin_amdgcn_mfma_f32_16x16x32_bf16(a0.s, b0, z, 0, 0, 0);
        acc[j] = __builtin_amdgcn_mfma_f32_16x16x32_bf16(a1.s, b1, acc[j], 0, 0, 0);
    }
    int rbase = gbase + wv * 16 + quad * 4;
    #pragma unroll
    for (int rr = 0; rr < 4; ++rr) {
        int orow = rbase + rr;
        if (orow < N) {
            float sc = dis[orow];
            #pragma unroll
            for (int j = 0; j < 4; ++j)
                Gout[(size_t)orow * D + j * 16 + m] = rnd_bf16(acc[j][rr] * sc);
        }
    }
}

// ---------------- final aggregation: out = di*(sum g) + b (fp32) ---------
// Same edge-centric phase 1; fp32 conversion epilogue.
__global__ __launch_bounds__(256) void k_agg(const ushort_t* __restrict__ G,
                                             const float* __restrict__ dis,
                                             const int2* __restrict__ rowse,
                                             const int* __restrict__ ssrc,
                                             const float* __restrict__ bias,
                                             float* __restrict__ out, int N) {
    __shared__ float hacc[64 * HS];
    int t = threadIdx.x;
    for (int i = t; i < 64 * HS; i += 256) hacc[i] = 0.f;
    int wv = t >> 6, lane = t & 63;
    int g = lane >> 3;
    int gid = wv * 8 + g;
    int c8 = (lane & 7) * 8;
    int gbase = blockIdx.x * 64;
    int last = gbase + 63; if (last > N - 1) last = N - 1;
    int rs = rowse[gbase].x;
    int re = rowse[last].y;
    int NV = N << 6;
    __syncthreads();
    edge_accum(G, ssrc, hacc, rs, re, gid, c8, NV);
    __syncthreads();
    int r = t >> 2, c16 = (t & 3) * 16;
    int node = gbase + r;
    if (node < N) {
        float di = dis[node];
        const float* hp = hacc + r * HS + c16;
        float4 h0 = *(const float4*)(hp + 0);
        float4 h1 = *(const float4*)(hp + 4);
        float4 h2 = *(const float4*)(hp + 8);
        float4 h3 = *(const float4*)(hp + 12);
        float4 b0 = *(const float4*)(bias + c16 + 0);
        float4 b1 = *(const float4*)(bias + c16 + 4);
        float4 b2 = *(const float4*)(bias + c16 + 8);
        float4 b3 = *(const float4*)(bias + c16 + 12);
        float4 r0, r1, r2, r3;
        r0.x = h0.x * di + b0.x; r0.y = h0.y * di + b0.y;
        r0.z = h0.z * di + b0.z; r0.w = h0.w * di + b0.w;
        r1.x = h1.x * di + b1.x; r1.y = h1.y * di + b1.y;
        r1.z = h1.z * di + b1.z; r1.w = h1.w * di + b1.w;
        r2.x = h2.x * di + b2.x; r2.y = h2.y * di + b2.y;
        r2.z = h2.z * di + b2.z; r2.w = h2.w * di + b2.w;
        r3.x = h3.x * di + b3.x; r3.y = h3.y * di + b3.y;
        r3.z = h3.z * di + b3.z; r3.w = h3.w * di + b3.w;
        float4* op = (float4*)(out + (size_t)node * D + c16);
        op[0] = r0; op[1] = r1; op[2] = r2; op[3] = r3;
    }
}

// ---------------- launch ----------------

extern "C" void kernel_launch(void* const* d_in, const int* in_sizes, int n_in,
                              void* d_out, int out_size, void* d_ws, size_t ws_size,
                              hipStream_t stream) {
    const float* x  = (const float*)d_in[0];
    const int*   ei = (const int*)d_in[1];
    const float* W0 = (const float*)d_in[2];
    const float* b0 = (const float*)d_in[3];
    const float* W1 = (const float*)d_in[4];
    const float* b1 = (const float*)d_in[5];
    const float* W2 = (const float*)d_in[6];
    const float* b2 = (const float*)d_in[7];
    float* out = (float*)d_out;

    const int N = in_sizes[0] / D;
    const int E = in_sizes[1] / 2;
    const int* e_src = ei;
    const int* e_dst = ei + E;

    const int nb = (N + BNODES - 1) >> RSHIFT;   // 196

    // workspace layout ((N+1) rows: row N is the zero pad row)
    size_t rowsz   = (size_t)(N + 1) * D;
    ushort_t* B0   = (ushort_t*)d_ws;                          // (N+1)*D bf16
    ushort_t* B1   = B0 + rowsz;                               // (N+1)*D bf16
    float* dis     = (float*)(B1 + rowsz);                     // N
    int2*  rowse   = (int2*)(dis + N);                         // N
    int*   ssrc    = (int*)(rowse + N);                        // nb*SCAP
    int*   bcur    = ssrc + (size_t)nb * SCAP;                 // MAXB
    int*   ebuf    = (int*)d_ws;    // nb*BCAP int = 8 MB, aliases B0 head
                                    // (dead before k_gemm0 writes B0)

    const int gG64 = (N + 63) / 64;              // 1563

    hipMemsetAsync(bcur, 0, MAXB * sizeof(int), stream);
    // zero pad-row N of both G buffers (never written by kernels)
    hipMemsetAsync(B0 + (size_t)N * D, 0, D * sizeof(ushort_t), stream);
    hipMemsetAsync(B1 + (size_t)N * D, 0, D * sizeof(ushort_t), stream);

    k_bucket<<<(E + 2047) / 2048, 256, 0, stream>>>(e_src, e_dst, bcur, ebuf, E, nb);
    k_csr<<<nb, 256, 0, stream>>>(ebuf, bcur, rowse, ssrc, dis, N, nb);

    // layer 0 gemm (MFMA, bf16 x in-register): x -> B0
    k_gemm0<<<gG64, 256, 0, stream>>>(x, W0, dis, B0, N);
    // fused agg(l0) + gemm(l1): B0 -> B1
    k_fagg<<<gG64, 256, 0, stream>>>(B0, dis, rowse, ssrc, b0, W1, B1, N);
    // fused agg(l1) + gemm(l2): B1 -> B0
    k_fagg<<<gG64, 256, 0, stream>>>(B1, dis, rowse, ssrc, b1, W2, B0, N);
    // final agg(l2): B0 -> out (fp32)
    k_agg<<<gG64, 256, 0, stream>>>(B0, dis, rowse, ssrc, b2, out, N);
}

// Round 6
// 241.763 us; speedup vs baseline: 9.9958x; 9.9958x over previous
//
#include <hip/hip_runtime.h>
#include <hip/hip_bf16.h>

#define D 64
#define RSHIFT 9             // 512 nodes per dst-bucket
#define BNODES 512
#define MAXB 256             // >= nb = ceil(100000/512) = 196
#define BCAP 10240           // per-bucket edge capacity (mean 8192, sigma ~90)
#define SCAP 14336           // per-bucket PADDED ssrc capacity
#define FH 72                // LDS row stride (bf16): 144B, 4-bank skew per row
#define EC 3072              // fagg per-block index stage (12 KB; mean ~1300 words)
#define ECA 2048             // agg per-block index stage (8 KB; mean ~650 words)

typedef unsigned short ushort_t;
typedef unsigned int uint_t;
typedef short short8 __attribute__((ext_vector_type(8)));   // 8 bf16 MFMA frag
typedef float floatx4 __attribute__((ext_vector_type(4)));  // MFMA C/D frag

__device__ inline uint_t pk_bf16(float x, float y) {
    uint_t ux = __float_as_uint(x); ux = ux + 0x7fffu + ((ux >> 16) & 1u);
    uint_t uy = __float_as_uint(y); uy = uy + 0x7fffu + ((uy >> 16) & 1u);
    return (ux >> 16) | (uy & 0xffff0000u);
}
__device__ inline ushort_t rnd_bf16(float x) {
    uint_t u = __float_as_uint(x); u = u + 0x7fffu + ((u >> 16) & 1u);
    return (ushort_t)(u >> 16);
}

// ---------------- stage 1: bucket edges by dst range ----------------
// Packed entry: (src << 9) | (dst & 511). NO per-edge global atomics.
__global__ __launch_bounds__(256) void k_bucket(const int* __restrict__ src,
                                                const int* __restrict__ dst,
                                                int* __restrict__ bcur,
                                                int* __restrict__ ebuf,
                                                int E, int nb) {
    __shared__ int lcnt[MAXB];
    __shared__ int lbase[MAXB];
    int t = threadIdx.x;
    lcnt[t] = 0;
    __syncthreads();
    int base = blockIdx.x * 2048 + t * 8;
    int sv[8], dv[8], sl[8];
    if (base + 7 < E) {
        int4 a0 = *(const int4*)(src + base);
        int4 a1 = *(const int4*)(src + base + 4);
        int4 b0 = *(const int4*)(dst + base);
        int4 b1 = *(const int4*)(dst + base + 4);
        sv[0]=a0.x; sv[1]=a0.y; sv[2]=a0.z; sv[3]=a0.w;
        sv[4]=a1.x; sv[5]=a1.y; sv[6]=a1.z; sv[7]=a1.w;
        dv[0]=b0.x; dv[1]=b0.y; dv[2]=b0.z; dv[3]=b0.w;
        dv[4]=b1.x; dv[5]=b1.y; dv[6]=b1.z; dv[7]=b1.w;
    } else {
        #pragma unroll
        for (int j = 0; j < 8; ++j) {
            dv[j] = (base + j < E) ? dst[base + j] : -1;
            sv[j] = (base + j < E) ? src[base + j] : 0;
        }
    }
    #pragma unroll
    for (int j = 0; j < 8; ++j) {
        if (dv[j] >= 0) {
            int b = dv[j] >> RSHIFT;
            sl[j] = atomicAdd(&lcnt[b], 1);   // LDS atomic only (int: native)
        }
    }
    __syncthreads();
    if (t < nb) { int c = lcnt[t]; if (c) lbase[t] = atomicAdd(&bcur[t], c); }
    __syncthreads();
    #pragma unroll
    for (int j = 0; j < 8; ++j) {
        if (dv[j] >= 0) {
            int b = dv[j] >> RSHIFT;
            int slot = lbase[b] + sl[j];
            if (slot < BCAP)
                ebuf[(size_t)b * BCAP + slot] = (sv[j] << RSHIFT) | (dv[j] & (BNODES - 1));
        }
    }
}

// ---------------- stage 2: per-bucket CSR build, all atomics in LDS -------
// Fixed per-bucket ssrc region (b*SCAP); per-node segments padded to x8
// (pads -> zero row N) so the gather loop is branch-free with int4 index
// loads. (R5 push/atomic variant reverted: 15x regression.)
__global__ __launch_bounds__(256) void k_csr(const int* __restrict__ ebuf,
                                             const int* __restrict__ bcur,
                                             int2* __restrict__ rowse,
                                             int* __restrict__ ssrc,
                                             float* __restrict__ dis,
                                             int N, int nb) {
    __shared__ int sseg[BCAP];        // 40 KB edge stage
    __shared__ int lcnt[BNODES];
    __shared__ int lcur[BNODES];
    __shared__ int sums[256];
    int b = blockIdx.x;
    int t = threadIdx.x;
    int n = bcur[b];
    if (n > BCAP) n = BCAP;
    int node0 = b << RSHIFT;
    #pragma unroll
    for (int i = t; i < BNODES; i += 256) lcnt[i] = 0;
    __syncthreads();
    const int* seg = ebuf + (size_t)b * BCAP;
    // count + stage edges into LDS
    for (int i = t * 4; i < n; i += 1024) {
        if (i + 3 < n) {
            int4 e = *(const int4*)(seg + i);
            *(int4*)(sseg + i) = e;
            atomicAdd(&lcnt[e.x & (BNODES - 1)], 1);
            atomicAdd(&lcnt[e.y & (BNODES - 1)], 1);
            atomicAdd(&lcnt[e.z & (BNODES - 1)], 1);
            atomicAdd(&lcnt[e.w & (BNODES - 1)], 1);
        } else {
            for (int j = 0; j < 4 && i + j < n; ++j) {
                int e = seg[i + j];
                sseg[i + j] = e;
                atomicAdd(&lcnt[e & (BNODES - 1)], 1);
            }
        }
    }
    __syncthreads();
    int idx = t * 2;
    int v0 = lcnt[idx], v1 = lcnt[idx + 1];
    int p0 = (v0 + 7) & ~7;           // padded lengths
    int p1 = (v1 + 7) & ~7;
    int s = p0 + p1;
    sums[t] = s;
    __syncthreads();
    for (int off = 1; off < 256; off <<= 1) {
        int x = (t >= off) ? sums[t - off] : 0;
        __syncthreads();
        sums[t] += x;
        __syncthreads();
    }
    int run = sums[t] - s;
    int beg0 = b * SCAP + run;
    int beg1 = beg0 + p0;
    lcur[idx] = beg0;
    lcur[idx + 1] = beg1;
    int node = node0 + idx;
    if (node < N)     { rowse[node]     = make_int2(beg0, beg0 + p0); dis[node]     = rsqrtf((float)(v0 + 1)); }
    if (node + 1 < N) { rowse[node + 1] = make_int2(beg1, beg1 + p1); dis[node + 1] = rsqrtf((float)(v1 + 1)); }
    __syncthreads();
    // single scatter pass from LDS stage
    for (int i = t * 4; i < n; i += 1024) {
        if (i + 3 < n) {
            int4 e = *(const int4*)(sseg + i);
            int q0 = atomicAdd(&lcur[e.x & (BNODES - 1)], 1); ssrc[q0] = e.x >> RSHIFT;
            int q1 = atomicAdd(&lcur[e.y & (BNODES - 1)], 1); ssrc[q1] = e.y >> RSHIFT;
            int q2 = atomicAdd(&lcur[e.z & (BNODES - 1)], 1); ssrc[q2] = e.z >> RSHIFT;
            int q3 = atomicAdd(&lcur[e.w & (BNODES - 1)], 1); ssrc[q3] = e.w >> RSHIFT;
        } else {
            for (int j = 0; j < 4 && i + j < n; ++j) {
                int e = sseg[i + j];
                int q = atomicAdd(&lcur[e & (BNODES - 1)], 1); ssrc[q] = e >> RSHIFT;
            }
        }
    }
    // fill pads with zero-row index N
    for (int k = v0; k < p0; ++k) ssrc[beg0 + k] = N;
    for (int k = v1; k < p1; ++k) ssrc[beg1 + k] = N;
}

// stage W^T as bf16 into LDS: wt[n][k] = bf16(W[k][n]) (validated R10)
__device__ __forceinline__ void stage_wt(const float* __restrict__ W,
                                         ushort_t* __restrict__ wt, int t) {
    const float4* W4 = (const float4*)W;
    for (int i = t; i < 1024; i += 256) {
        float4 w4 = W4[i];
        int k = i >> 4, n0 = (i & 15) * 4;
        wt[(n0 + 0) * FH + k] = rnd_bf16(w4.x);
        wt[(n0 + 1) * FH + k] = rnd_bf16(w4.y);
        wt[(n0 + 2) * FH + k] = rnd_bf16(w4.z);
        wt[(n0 + 3) * FH + k] = rnd_bf16(w4.w);
    }
}

// ---------------- layer-0 GEMM via MFMA: G = bf16((x@W)*dis) -------------
__global__ __launch_bounds__(256) void k_gemm0(const float* __restrict__ x,
                                               const float* __restrict__ W,
                                               const float* __restrict__ dis,
                                               ushort_t* __restrict__ G, int N) {
    __shared__ ushort_t wt[64 * FH];
    int t = threadIdx.x;
    stage_wt(W, wt, t);
    __syncthreads();
    int wv = t >> 6, lane = t & 63;
    int m = lane & 15, quad = lane >> 4;
    int row = blockIdx.x * 64 + wv * 16 + m;
    long rowc = (row < N) ? row : (N - 1);
    float4 f0 = *(const float4*)(x + rowc * D + quad * 8);
    float4 f1 = *(const float4*)(x + rowc * D + quad * 8 + 4);
    float4 f2 = *(const float4*)(x + rowc * D + 32 + quad * 8);
    float4 f3 = *(const float4*)(x + rowc * D + 32 + quad * 8 + 4);
    union { short8 s; uint_t u[4]; } a0, a1;
    a0.u[0] = pk_bf16(f0.x, f0.y); a0.u[1] = pk_bf16(f0.z, f0.w);
    a0.u[2] = pk_bf16(f1.x, f1.y); a0.u[3] = pk_bf16(f1.z, f1.w);
    a1.u[0] = pk_bf16(f2.x, f2.y); a1.u[1] = pk_bf16(f2.z, f2.w);
    a1.u[2] = pk_bf16(f3.x, f3.y); a1.u[3] = pk_bf16(f3.z, f3.w);
    floatx4 acc[4];
    #pragma unroll
    for (int j = 0; j < 4; ++j) {
        short8 b0 = *(short8*)&wt[(j * 16 + m) * FH + quad * 8];
        short8 b1 = *(short8*)&wt[(j * 16 + m) * FH + 32 + quad * 8];
        floatx4 z = {0.f, 0.f, 0.f, 0.f};
        acc[j] = __builtin_amdgcn_mfma_f32_16x16x32_bf16(a0.s, b0, z, 0, 0, 0);
        acc[j] = __builtin_amdgcn_mfma_f32_16x16x32_bf16(a1.s, b1, acc[j], 0, 0, 0);
    }
    int rbase = blockIdx.x * 64 + wv * 16 + quad * 4;
    #pragma unroll
    for (int r = 0; r < 4; ++r) {
        int rr = rbase + r;
        if (rr < N) {
            float sc = dis[rr];
            #pragma unroll
            for (int j = 0; j < 4; ++j)
                G[(size_t)rr * D + j * 16 + m] = rnd_bf16(acc[j][r] * sc);
        }
    }
}

// ---- pull-gather one node with an 8-lane group (R3 pipelined core) ------
// sp points at the node's index words — either the LDS stage (common: one
// global round-trip removed from the per-node prologue; ds_read broadcast
// across the group's 8 lanes) or global ssrc (overflow fallback). Both
// call sites are separately inlined so addrspace inference specializes.
__device__ __forceinline__ void gather_core(const ushort_t* __restrict__ G,
                                            const int4* sp, int n8, int c8,
                                            int node, float a[8]) {
    #pragma unroll
    for (int j = 0; j < 8; ++j) a[j] = 0.f;
    #define ROW(i) (*(const uint4*)(G + (size_t)(i) * D + c8))
    #define ACC1(u)                                                        \
        {                                                                  \
            a[0] += __uint_as_float(u.x << 16);                            \
            a[1] += __uint_as_float(u.x & 0xffff0000u);                    \
            a[2] += __uint_as_float(u.y << 16);                            \
            a[3] += __uint_as_float(u.y & 0xffff0000u);                    \
            a[4] += __uint_as_float(u.z << 16);                            \
            a[5] += __uint_as_float(u.z & 0xffff0000u);                    \
            a[6] += __uint_as_float(u.w << 16);                            \
            a[7] += __uint_as_float(u.w & 0xffff0000u);                    \
        }
    uint4 su = ROW(node);
    if (n8 > 0) {
        int4 ia = sp[0], ib = sp[1];
        uint4 u0 = ROW(ia.x), u1 = ROW(ia.y), u2 = ROW(ia.z), u3 = ROW(ia.w);
        uint4 u4 = ROW(ib.x), u5 = ROW(ib.y), u6 = ROW(ib.z), u7 = ROW(ib.w);
        if (n8 > 1) { ia = sp[2]; ib = sp[3]; }
        for (int ch = 1; ch < n8; ++ch) {
            uint4 v0 = ROW(ia.x), v1 = ROW(ia.y), v2 = ROW(ia.z), v3 = ROW(ia.w);
            uint4 v4 = ROW(ib.x), v5 = ROW(ib.y), v6 = ROW(ib.z), v7 = ROW(ib.w);
            if (ch + 1 < n8) { ia = sp[2 * ch + 2]; ib = sp[2 * ch + 3]; }
            ACC1(u0); ACC1(u1); ACC1(u2); ACC1(u3);
            ACC1(u4); ACC1(u5); ACC1(u6); ACC1(u7);
            u0 = v0; u1 = v1; u2 = v2; u3 = v3;
            u4 = v4; u5 = v5; u6 = v6; u7 = v7;
        }
        ACC1(u0); ACC1(u1); ACC1(u2); ACC1(u3);
        ACC1(u4); ACC1(u5); ACC1(u6); ACC1(u7);
    }
    ACC1(su);   // self-loop last: its load latency hid under the chunks
    #undef ACC1
    #undef ROW
}

// ---------------- fused agg + next-layer MFMA gemm -----------------------
// Phase 0: cooperatively stage the block's contiguous index range [rs,re)
// into LDS. Phase 1: 4 waves x 8 groups x 2 nodes, indices from LDS.
// Phase 2: 8 MFMA per wave.
__global__ __launch_bounds__(256) void k_fagg(const ushort_t* __restrict__ G,
                                              const float* __restrict__ dis,
                                              const int2* __restrict__ rowse,
                                              const int* __restrict__ ssrc,
                                              const float* __restrict__ bias,
                                              const float* __restrict__ W,
                                              ushort_t* __restrict__ Gout,
                                              int N) {
    __shared__ ushort_t hbuf[64 * FH];   // 9.2 KB
    __shared__ ushort_t wt[64 * FH];     // 9.2 KB
    __shared__ int sidx[EC];             // 12 KB index stage
    int t = threadIdx.x;
    stage_wt(W, wt, t);
    int gbase = blockIdx.x * 64;
    int last = gbase + 63; if (last > N - 1) last = N - 1;
    int rs = rowse[gbase].x;
    int re = rowse[last].y;
    int scnt = re - rs; if (scnt > EC) scnt = EC;   // multiple of 8
    for (int i = t * 4; i < scnt; i += 1024)
        *(int4*)(sidx + i) = *(const int4*)(ssrc + rs + i);
    __syncthreads();
    int wv = t >> 6, lane = t & 63;
    int g = lane >> 3;
    int c8 = (lane & 7) * 8;
    float4 bv0 = *(const float4*)(bias + c8);
    float4 bv1 = *(const float4*)(bias + c8 + 4);
    for (int ii = 0; ii < 2; ++ii) {
        int idx = wv * 16 + ii * 8 + g;
        int node = gbase + idx;
        if (node < N) {
            int2 se = rowse[node];
            float di = dis[node];
            int off = se.x - rs, len = se.y - se.x, n8 = len >> 3;
            float a[8];
            if (off + len <= EC)
                gather_core(G, (const int4*)(sidx + off), n8, c8, node, a);
            else
                gather_core(G, (const int4*)(ssrc + se.x), n8, c8, node, a);
            uint4 p;
            p.x = pk_bf16(a[0] * di + bv0.x, a[1] * di + bv0.y);
            p.y = pk_bf16(a[2] * di + bv0.z, a[3] * di + bv0.w);
            p.z = pk_bf16(a[4] * di + bv1.x, a[5] * di + bv1.y);
            p.w = pk_bf16(a[6] * di + bv1.z, a[7] * di + bv1.w);
            *(uint4*)&hbuf[idx * FH + c8] = p;
        }
    }
    __syncthreads();
    // phase 2: MFMA (layout validated R10)
    int m = lane & 15, quad = lane >> 4;
    short8 a0 = *(short8*)&hbuf[(wv * 16 + m) * FH + quad * 8];
    short8 a1 = *(short8*)&hbuf[(wv * 16 + m) * FH + 32 + quad * 8];
    floatx4 acc[4];
    #pragma unroll
    for (int j = 0; j < 4; ++j) {
        short8 b0 = *(short8*)&wt[(j * 16 + m) * FH + quad * 8];
        short8 b1 = *(short8*)&wt[(j * 16 + m) * FH + 32 + quad * 8];
        floatx4 z = {0.f, 0.f, 0.f, 0.f};
        acc[j] = __builtin_amdgcn_mfma_f32_16x16x32_bf16(a0, b0, z, 0, 0, 0);
        acc[j] = __builtin_amdgcn_mfma_f32_16x16x32_bf16(a1, b1, acc[j], 0, 0, 0);
    }
    int rbase = gbase + wv * 16 + quad * 4;
    #pragma unroll
    for (int r = 0; r < 4; ++r) {
        int row = rbase + r;
        if (row < N) {
            float sc = dis[row];
            #pragma unroll
            for (int j = 0; j < 4; ++j)
                Gout[(size_t)row * D + j * 16 + m] = rnd_bf16(acc[j][r] * sc);
        }
    }
}

// ---------------- final aggregation: out = di*(sum g) + b (fp32) ---------
// One node per 8-lane group; 32 nodes per block; LDS index stage.
__global__ __launch_bounds__(256) void k_agg(const ushort_t* __restrict__ G,
                                             const float* __restrict__ dis,
                                             const int2* __restrict__ rowse,
                                             const int* __restrict__ ssrc,
                                             const float* __restrict__ bias,
                                             float* __restrict__ out, int N) {
    __shared__ int sidx[ECA];            // 8 KB index stage
    int t = threadIdx.x;
    int base = blockIdx.x * 32;
    int last = base + 31; if (last > N - 1) last = N - 1;
    int rs = rowse[base].x;
    int re = rowse[last].y;
    int scnt = re - rs; if (scnt > ECA) scnt = ECA;
    for (int i = t * 4; i < scnt; i += 1024)
        *(int4*)(sidx + i) = *(const int4*)(ssrc + rs + i);
    __syncthreads();
    int wv = t >> 6, lane = t & 63;
    int g = lane >> 3;
    int c8 = (lane & 7) * 8;
    int node = base + wv * 8 + g;
    if (node >= N) return;
    int2 se = rowse[node];
    float di = dis[node];
    int off = se.x - rs, len = se.y - se.x, n8 = len >> 3;
    float a[8];
    if (off + len <= ECA)
        gather_core(G, (const int4*)(sidx + off), n8, c8, node, a);
    else
        gather_core(G, (const int4*)(ssrc + se.x), n8, c8, node, a);
    float4 bv0 = *(const float4*)(bias + c8);
    float4 bv1 = *(const float4*)(bias + c8 + 4);
    float4 r0, r1;
    r0.x = a[0] * di + bv0.x; r0.y = a[1] * di + bv0.y;
    r0.z = a[2] * di + bv0.z; r0.w = a[3] * di + bv0.w;
    r1.x = a[4] * di + bv1.x; r1.y = a[5] * di + bv1.y;
    r1.z = a[6] * di + bv1.z; r1.w = a[7] * di + bv1.w;
    float4* op = (float4*)(out + (size_t)node * D + c8);
    op[0] = r0;
    op[1] = r1;
}

// ---------------- launch ----------------

extern "C" void kernel_launch(void* const* d_in, const int* in_sizes, int n_in,
                              void* d_out, int out_size, void* d_ws, size_t ws_size,
                              hipStream_t stream) {
    const float* x  = (const float*)d_in[0];
    const int*   ei = (const int*)d_in[1];
    const float* W0 = (const float*)d_in[2];
    const float* b0 = (const float*)d_in[3];
    const float* W1 = (const float*)d_in[4];
    const float* b1 = (const float*)d_in[5];
    const float* W2 = (const float*)d_in[6];
    const float* b2 = (const float*)d_in[7];
    float* out = (float*)d_out;

    const int N = in_sizes[0] / D;
    const int E = in_sizes[1] / 2;
    const int* e_src = ei;
    const int* e_dst = ei + E;

    const int nb = (N + BNODES - 1) >> RSHIFT;   // 196

    // workspace layout ((N+1) rows: row N is the zero pad row)
    size_t rowsz   = (size_t)(N + 1) * D;
    ushort_t* B0   = (ushort_t*)d_ws;                          // (N+1)*D bf16
    ushort_t* B1   = B0 + rowsz;                               // (N+1)*D bf16
    float* dis     = (float*)(B1 + rowsz);                     // N
    int2*  rowse   = (int2*)(dis + N);                         // N
    int*   ssrc    = (int*)(rowse + N);                        // nb*SCAP
    int*   bcur    = ssrc + (size_t)nb * SCAP;                 // MAXB
    int*   ebuf    = (int*)d_ws;    // nb*BCAP int = 8 MB, aliases B0 head
                                    // (dead before k_gemm0 writes B0)

    const int gG64 = (N + 63) / 64;              // 1563
    const int gAgg = (N + 31) / 32;              // 3125

    hipMemsetAsync(bcur, 0, MAXB * sizeof(int), stream);
    // zero pad-row N of both G buffers (never written by kernels)
    hipMemsetAsync(B0 + (size_t)N * D, 0, D * sizeof(ushort_t), stream);
    hipMemsetAsync(B1 + (size_t)N * D, 0, D * sizeof(ushort_t), stream);

    k_bucket<<<(E + 2047) / 2048, 256, 0, stream>>>(e_src, e_dst, bcur, ebuf, E, nb);
    k_csr<<<nb, 256, 0, stream>>>(ebuf, bcur, rowse, ssrc, dis, N, nb);

    // layer 0 gemm (MFMA, bf16 x in-register): x -> B0
    k_gemm0<<<gG64, 256, 0, stream>>>(x, W0, dis, B0, N);
    // fused agg(l0) + gemm(l1): B0 -> B1
    k_fagg<<<gG64, 256, 0, stream>>>(B0, dis, rowse, ssrc, b0, W1, B1, N);
    // fused agg(l1) + gemm(l2): B1 -> B0
    k_fagg<<<gG64, 256, 0, stream>>>(B1, dis, rowse, ssrc, b1, W2, B0, N);
    // final agg(l2): B0 -> out (fp32)
    k_agg<<<gAgg, 256, 0, stream>>>(B0, dis, rowse, ssrc, b2, out, N);
}